// Round 1
// 3226.099 us; speedup vs baseline: 1.2388x; 1.2388x over previous
//
#include <hip/hip_runtime.h>
#include <math.h>

#define N_NODES 325
#define GTOT    2016
#define NPOS    655200      // GTOT * N_NODES
#define NEDGE   2600
#define EBTOT   2925        // NEDGE + N_NODES (self loops)

static __device__ __forceinline__ float bf2f(unsigned short u) {
  union { unsigned int i; float f; } x; x.i = ((unsigned int)u) << 16; return x.f;
}
static __device__ __forceinline__ unsigned short f2bf(float v) {
  union { unsigned int i; float f; } x; x.f = v;
  unsigned int r = x.i + 0x7fffu + ((x.i >> 16) & 1u);
  return (unsigned short)(r >> 16);
}
static __device__ __forceinline__ float sigm(float v) { return 1.f / (1.f + __expf(-v)); }

// ---------------- CSR build (dst-major, self loops appended) ----------------
__global__ void k_csr(const int* __restrict__ ei, int* __restrict__ rowp,
                      int* __restrict__ cols) {
  __shared__ int cnt[N_NODES];
  __shared__ int offs[N_NODES];
  const int tid = threadIdx.x;
  for (int i = tid; i < N_NODES; i += blockDim.x) cnt[i] = 0;
  __syncthreads();
  for (int e = tid; e < EBTOT; e += blockDim.x) {
    int dst = (e < NEDGE) ? ei[NEDGE + e] : (e - NEDGE);
    atomicAdd(&cnt[dst], 1);
  }
  __syncthreads();
  if (tid == 0) {
    int run = 0;
    for (int i = 0; i < N_NODES; ++i) { offs[i] = run; rowp[i] = run; run += cnt[i]; }
    rowp[N_NODES] = run;
  }
  __syncthreads();
  for (int e = tid; e < EBTOT; e += blockDim.x) {
    int src, dst;
    if (e < NEDGE) { src = ei[e]; dst = ei[NEDGE + e]; }
    else           { src = e - NEDGE; dst = src; }
    int pos = atomicAdd(&offs[dst], 1);
    cols[pos] = src;
  }
}

// ---------------- GRU (input 1 -> hidden 32, K=12) + proj MLP 32->32->32 ----
__global__ __launch_bounds__(256) void k_gru(
    const float* __restrict__ seq,
    const float* __restrict__ w_ih, const float* __restrict__ w_hh,
    const float* __restrict__ b_ih, const float* __restrict__ b_hh,
    const float* __restrict__ rw1, const float* __restrict__ rb1,
    const float* __restrict__ rw2, const float* __restrict__ rb2,
    float* __restrict__ recent) {
  __shared__ float h[8][33];
  __shared__ float h2[8][33];
  const int tid = threadIdx.x;
  const int ln = tid >> 5, j = tid & 31;
  const int n = blockIdx.x * 8 + ln;
  h[ln][j] = 0.f;
  __syncthreads();
  for (int t = 0; t < 12; ++t) {
    float x = (n < N_NODES) ? seq[n * 12 + t] : 0.f;
    float i_r = fmaf(x, w_ih[j],      b_ih[j]);
    float i_z = fmaf(x, w_ih[32 + j], b_ih[32 + j]);
    float i_n = fmaf(x, w_ih[64 + j], b_ih[64 + j]);
    float h_r = b_hh[j], h_z = b_hh[32 + j], h_n = b_hh[64 + j];
    #pragma unroll
    for (int k = 0; k < 32; ++k) {
      float hk = h[ln][k];
      h_r = fmaf(hk, w_hh[k * 96 + j],      h_r);
      h_z = fmaf(hk, w_hh[k * 96 + 32 + j], h_z);
      h_n = fmaf(hk, w_hh[k * 96 + 64 + j], h_n);
    }
    float r  = sigm(i_r + h_r);
    float z  = sigm(i_z + h_z);
    float nn = tanhf(fmaf(r, h_n, i_n));
    float hw = (1.f - z) * nn + z * h[ln][j];
    __syncthreads();
    h[ln][j] = hw;
    __syncthreads();
  }
  float a = rb1[j];
  #pragma unroll
  for (int k = 0; k < 32; ++k) a = fmaf(h[ln][k], rw1[k * 32 + j], a);
  h2[ln][j] = fmaxf(a, 0.f);
  __syncthreads();
  float o = rb2[j];
  #pragma unroll
  for (int k = 0; k < 32; ++k) o = fmaf(h2[ln][k], rw2[k * 32 + j], o);
  if (n < N_NODES) recent[n * 32 + j] = o;
}

// ---------------- calendar encoder: 2016 x (29 -> 32 -> 32) ----------------
__global__ __launch_bounds__(256) void k_cal(
    const float* __restrict__ wemb, const float* __restrict__ semb,
    const float* __restrict__ w1, const float* __restrict__ b1,
    const float* __restrict__ w2, const float* __restrict__ b2,
    float* __restrict__ cal) {
  __shared__ float feat[8][32];
  __shared__ float hid[8][33];
  const int tid = threadIdx.x;
  const int ln = tid >> 5, j = tid & 31;
  const int pos = blockIdx.x * 8 + ln;   // pos = w*288 + s
  const int w = pos / 288, s = pos - w * 288;
  const float TWO_PI = 6.283185307179586f;
  float f = 0.f;
  if (j < 8)       f = wemb[w * 8 + j];
  else if (j < 24) f = semb[s * 16 + (j - 8)];
  else if (j == 24) f = sinf(TWO_PI * (float)s / 288.f);
  else if (j == 25) f = cosf(TWO_PI * (float)s / 288.f);
  else if (j == 26) f = sinf(TWO_PI * (float)w / 7.f);
  else if (j == 27) f = cosf(TWO_PI * (float)w / 7.f);
  else if (j == 28) f = (w >= 5) ? 1.f : 0.f;
  feat[ln][j] = f;
  __syncthreads();
  float a = b1[j];
  #pragma unroll
  for (int k = 0; k < 29; ++k) a = fmaf(feat[ln][k], w1[k * 32 + j], a);
  hid[ln][j] = fmaxf(a, 0.f);
  __syncthreads();
  float o = b2[j];
  #pragma unroll
  for (int k = 0; k < 32; ++k) o = fmaf(hid[ln][k], w2[k * 32 + j], o);
  if (pos < GTOT) cal[pos * 32 + j] = o;
}

// ---------------- fusion: delta = (relu(f@W1+b1)@W2+b2) * sigmoid(f@Wg+bg) --
__global__ __launch_bounds__(256, 2) void k_fusion(
    const float* __restrict__ Hb, const float* __restrict__ recent,
    const float* __restrict__ cal,
    const float* __restrict__ dw1, const float* __restrict__ db1,
    const float* __restrict__ dw2, const float* __restrict__ db2,
    const float* __restrict__ gw,  const float* __restrict__ gb,
    float* __restrict__ delta) {
  __shared__ float fu[64 * 130];
  __shared__ float hid[64 * 66];
  const int tid = threadIdx.x;
  const int p0 = blockIdx.x * 64;
  for (int idx = tid; idx < 64 * 128; idx += 256) {
    int pl = idx >> 7, k = idx & 127;
    int p = p0 + pl;
    float v = 0.f;
    if (p < NPOS) {
      int g = p / N_NODES;
      int n = p - g * N_NODES;
      if (k < 64)      v = Hb[(size_t)p * 64 + k];
      else if (k < 96) v = recent[n * 32 + (k - 64)];
      else             v = cal[g * 32 + (k - 96)];
    }
    fu[pl * 130 + k] = v;
  }
  __syncthreads();
  const int j0  = (tid & 7) * 8;
  const int pl0 = (tid >> 3) * 2;
  const float* fr0 = fu + pl0 * 130;
  const float* fr1 = fr0 + 130;

  float a0[8], a1[8];
  #pragma unroll
  for (int jj = 0; jj < 8; ++jj) { a0[jj] = db1[j0 + jj]; a1[jj] = a0[jj]; }
  #pragma unroll 2
  for (int k = 0; k < 128; ++k) {
    float4 wa = *(const float4*)(dw1 + k * 64 + j0);
    float4 wb = *(const float4*)(dw1 + k * 64 + j0 + 4);
    float f0 = fr0[k], f1 = fr1[k];
    a0[0]=fmaf(f0,wa.x,a0[0]); a1[0]=fmaf(f1,wa.x,a1[0]);
    a0[1]=fmaf(f0,wa.y,a0[1]); a1[1]=fmaf(f1,wa.y,a1[1]);
    a0[2]=fmaf(f0,wa.z,a0[2]); a1[2]=fmaf(f1,wa.z,a1[2]);
    a0[3]=fmaf(f0,wa.w,a0[3]); a1[3]=fmaf(f1,wa.w,a1[3]);
    a0[4]=fmaf(f0,wb.x,a0[4]); a1[4]=fmaf(f1,wb.x,a1[4]);
    a0[5]=fmaf(f0,wb.y,a0[5]); a1[5]=fmaf(f1,wb.y,a1[5]);
    a0[6]=fmaf(f0,wb.z,a0[6]); a1[6]=fmaf(f1,wb.z,a1[6]);
    a0[7]=fmaf(f0,wb.w,a0[7]); a1[7]=fmaf(f1,wb.w,a1[7]);
  }
  float* hr0 = hid + pl0 * 66;
  float* hr1 = hr0 + 66;
  #pragma unroll
  for (int jj = 0; jj < 8; ++jj) {
    hr0[j0 + jj] = fmaxf(a0[jj], 0.f);
    hr1[j0 + jj] = fmaxf(a1[jj], 0.f);
  }
  __syncthreads();

  float g0[8], g1[8];
  #pragma unroll
  for (int jj = 0; jj < 8; ++jj) { g0[jj] = gb[j0 + jj]; g1[jj] = g0[jj]; }
  #pragma unroll 2
  for (int k = 0; k < 128; ++k) {
    float4 wa = *(const float4*)(gw + k * 64 + j0);
    float4 wb = *(const float4*)(gw + k * 64 + j0 + 4);
    float f0 = fr0[k], f1 = fr1[k];
    g0[0]=fmaf(f0,wa.x,g0[0]); g1[0]=fmaf(f1,wa.x,g1[0]);
    g0[1]=fmaf(f0,wa.y,g0[1]); g1[1]=fmaf(f1,wa.y,g1[1]);
    g0[2]=fmaf(f0,wa.z,g0[2]); g1[2]=fmaf(f1,wa.z,g1[2]);
    g0[3]=fmaf(f0,wa.w,g0[3]); g1[3]=fmaf(f1,wa.w,g1[3]);
    g0[4]=fmaf(f0,wb.x,g0[4]); g1[4]=fmaf(f1,wb.x,g1[4]);
    g0[5]=fmaf(f0,wb.y,g0[5]); g1[5]=fmaf(f1,wb.y,g1[5]);
    g0[6]=fmaf(f0,wb.z,g0[6]); g1[6]=fmaf(f1,wb.z,g1[6]);
    g0[7]=fmaf(f0,wb.w,g0[7]); g1[7]=fmaf(f1,wb.w,g1[7]);
  }
  float d0[8], d1[8];
  #pragma unroll
  for (int jj = 0; jj < 8; ++jj) { d0[jj] = db2[j0 + jj]; d1[jj] = d0[jj]; }
  #pragma unroll 2
  for (int k = 0; k < 64; ++k) {
    float4 wa = *(const float4*)(dw2 + k * 64 + j0);
    float4 wb = *(const float4*)(dw2 + k * 64 + j0 + 4);
    float h0 = hr0[k], h1 = hr1[k];
    d0[0]=fmaf(h0,wa.x,d0[0]); d1[0]=fmaf(h1,wa.x,d1[0]);
    d0[1]=fmaf(h0,wa.y,d0[1]); d1[1]=fmaf(h1,wa.y,d1[1]);
    d0[2]=fmaf(h0,wa.z,d0[2]); d1[2]=fmaf(h1,wa.z,d1[2]);
    d0[3]=fmaf(h0,wa.w,d0[3]); d1[3]=fmaf(h1,wa.w,d1[3]);
    d0[4]=fmaf(h0,wb.x,d0[4]); d1[4]=fmaf(h1,wb.x,d1[4]);
    d0[5]=fmaf(h0,wb.y,d0[5]); d1[5]=fmaf(h1,wb.y,d1[5]);
    d0[6]=fmaf(h0,wb.z,d0[6]); d1[6]=fmaf(h1,wb.z,d1[6]);
    d0[7]=fmaf(h0,wb.w,d0[7]); d1[7]=fmaf(h1,wb.w,d1[7]);
  }
  int pA = p0 + pl0;
  if (pA < NPOS) {
    float4 o;
    o.x=d0[0]*sigm(g0[0]); o.y=d0[1]*sigm(g0[1]); o.z=d0[2]*sigm(g0[2]); o.w=d0[3]*sigm(g0[3]);
    *(float4*)(delta + (size_t)pA * 64 + j0) = o;
    o.x=d0[4]*sigm(g0[4]); o.y=d0[5]*sigm(g0[5]); o.z=d0[6]*sigm(g0[6]); o.w=d0[7]*sigm(g0[7]);
    *(float4*)(delta + (size_t)pA * 64 + j0 + 4) = o;
  }
  if (pA + 1 < NPOS) {
    float4 o;
    o.x=d1[0]*sigm(g1[0]); o.y=d1[1]*sigm(g1[1]); o.z=d1[2]*sigm(g1[2]); o.w=d1[3]*sigm(g1[3]);
    *(float4*)(delta + (size_t)(pA + 1) * 64 + j0) = o;
    o.x=d1[4]*sigm(g1[4]); o.y=d1[5]*sigm(g1[5]); o.z=d1[6]*sigm(g1[6]); o.w=d1[7]*sigm(g1[7]);
    *(float4*)(delta + (size_t)(pA + 1) * 64 + j0 + 4) = o;
  }
}

// ---------------- GAT layer 1: heads=2, mean, +bias, relu -------------------
// W column held in VGPRs (loaded once/head); attention logits fused into
// phase 1 via wave shuffle-reduce; per-edge leaky logits precomputed (bf16,
// LDS); edge aggregation unrolled 4-wide with independent partials.
__global__ __launch_bounds__(256, 3) void k_gat1(
    const float* __restrict__ x,       // delta  [2016,325,64]
    const int* __restrict__ rowp, const int* __restrict__ cols,
    const float* __restrict__ W,       // [64,128]
    const float* __restrict__ att_s, const float* __restrict__ att_d, // [2,64]
    const float* __restrict__ bias,    // [64]
    float* __restrict__ y) {           // [2016,325,64]
  __shared__ unsigned short xp[N_NODES * 66];   // 42,900 B
  __shared__ float as_[N_NODES];
  __shared__ float ad_[N_NODES];
  __shared__ unsigned short lw[EBTOT + 3];      // 5,856 B  (bf16 leaky logits)
  const int tid = threadIdx.x;
  const int lane = tid & 63;
  const int wv = tid >> 6;
  const int c = blockIdx.x;
  const float* xc = x + (size_t)c * (N_NODES * 64);
  float* yc = y + (size_t)c * (N_NODES * 64);
  const float blane = bias[lane];
  for (int h = 0; h < 2; ++h) {
    // ---- phase 1: xp = x[c] @ W[:,h*64:(h+1)*64]  + fused attention logits
    {
      float wreg[64];
      const float* wcol = W + h * 64 + lane;
      #pragma unroll
      for (int q = 0; q < 64; ++q) wreg[q] = wcol[q * 128];
      const float atts = att_s[h * 64 + lane];
      const float attd = att_d[h * 64 + lane];
      for (int n = wv; n < N_NODES; n += 4) {
        const float4* xr = (const float4*)(xc + n * 64);
        float a0 = 0.f, a1 = 0.f, a2 = 0.f, a3 = 0.f;
        #pragma unroll
        for (int q4 = 0; q4 < 16; ++q4) {
          float4 xv = xr[q4];
          a0 = fmaf(xv.x, wreg[4 * q4 + 0], a0);
          a1 = fmaf(xv.y, wreg[4 * q4 + 1], a1);
          a2 = fmaf(xv.z, wreg[4 * q4 + 2], a2);
          a3 = fmaf(xv.w, wreg[4 * q4 + 3], a3);
        }
        float acc = (a0 + a1) + (a2 + a3);
        xp[n * 66 + lane] = f2bf(acc);
        float ps = acc * atts, pd = acc * attd;
        #pragma unroll
        for (int off = 32; off; off >>= 1) {
          ps += __shfl_xor(ps, off);
          pd += __shfl_xor(pd, off);
        }
        if (lane == 0) { as_[n] = ps; ad_[n] = pd; }
      }
    }
    __syncthreads();
    // ---- phase 2: per-edge leaky logits (parallel over dsts)
    for (int d = tid; d < N_NODES; d += 256) {
      int rb = rowp[d], re = rowp[d + 1];
      float adv = ad_[d];
      for (int e = rb; e < re; ++e) {
        float v = as_[cols[e]] + adv;
        lw[e] = f2bf((v >= 0.f) ? v : 0.2f * v);
      }
    }
    __syncthreads();
    // ---- phase 3: per-dst softmax + aggregate (one wave per dst, 4-wide ILP)
    for (int d = wv; d < N_NODES; d += 4) {
      int rb = __builtin_amdgcn_readfirstlane(rowp[d]);
      int re = __builtin_amdgcn_readfirstlane(rowp[d + 1]);
      float prev = (h == 1) ? yc[d * 64 + lane] : 0.f;  // prefetch before chain
      float dn0 = 0.f, dn1 = 0.f, dn2 = 0.f, dn3 = 0.f;
      float ac0 = 0.f, ac1 = 0.f, ac2 = 0.f, ac3 = 0.f;
      for (int e0 = rb; e0 < re; e0 += 4) {
        int e1 = e0 + 1, e2 = e0 + 2, e3 = e0 + 3;
        bool k1 = e1 < re, k2 = e2 < re, k3 = e3 < re;
        int s0 = cols[e0];
        int s1 = cols[k1 ? e1 : e0];
        int s2 = cols[k2 ? e2 : e0];
        int s3 = cols[k3 ? e3 : e0];
        float w0 = __expf(bf2f(lw[e0]));
        float w1 = k1 ? __expf(bf2f(lw[e1])) : 0.f;
        float w2 = k2 ? __expf(bf2f(lw[e2])) : 0.f;
        float w3 = k3 ? __expf(bf2f(lw[e3])) : 0.f;
        dn0 += w0; dn1 += w1; dn2 += w2; dn3 += w3;
        ac0 = fmaf(w0, bf2f(xp[s0 * 66 + lane]), ac0);
        ac1 = fmaf(w1, bf2f(xp[s1 * 66 + lane]), ac1);
        ac2 = fmaf(w2, bf2f(xp[s2 * 66 + lane]), ac2);
        ac3 = fmaf(w3, bf2f(xp[s3 * 66 + lane]), ac3);
      }
      float den = (dn0 + dn1) + (dn2 + dn3);
      float acc = (ac0 + ac1) + (ac2 + ac3);
      float o = acc / (den + 1e-16f);
      if (h == 0) {
        yc[d * 64 + lane] = o;                  // partial (head 0)
      } else {
        yc[d * 64 + lane] = fmaxf(0.5f * (prev + o) + blane, 0.f);
      }
    }
    __syncthreads();
  }
}

// ---------------- GAT layer 2 (1 head) + residual + speed head --------------
__global__ __launch_bounds__(256, 3) void k_gat2(
    const float* x,                     // y1 (same buffer as dR - no restrict)
    const float* __restrict__ Hb,
    const int* __restrict__ rowp, const int* __restrict__ cols,
    const float* __restrict__ W,        // [64,64]
    const float* __restrict__ att_s, const float* __restrict__ att_d, // [64]
    const float* __restrict__ bias,
    const float* __restrict__ shw1, const float* __restrict__ shb1,
    const float* __restrict__ shw2, const float* __restrict__ shb2,
    float* dR, float* __restrict__ Ha, float* __restrict__ pred) {
  __shared__ unsigned short xp[N_NODES * 66];
  __shared__ float as_[N_NODES];
  __shared__ float ad_[N_NODES];
  __shared__ unsigned short lw[EBTOT + 3];
  __shared__ float hv[4][68];
  const int tid = threadIdx.x;
  const int lane = tid & 63;
  const int wv = tid >> 6;
  const int c = blockIdx.x;
  const float* xc = x + (size_t)c * (N_NODES * 64);
  const float blane = bias[lane];
  // ---- phase 1 (W column in regs, fused logits)
  {
    float wreg[64];
    const float* wcol = W + lane;
    #pragma unroll
    for (int q = 0; q < 64; ++q) wreg[q] = wcol[q * 64];
    const float atts = att_s[lane];
    const float attd = att_d[lane];
    for (int n = wv; n < N_NODES; n += 4) {
      const float4* xr = (const float4*)(xc + n * 64);
      float a0 = 0.f, a1 = 0.f, a2 = 0.f, a3 = 0.f;
      #pragma unroll
      for (int q4 = 0; q4 < 16; ++q4) {
        float4 xv = xr[q4];
        a0 = fmaf(xv.x, wreg[4 * q4 + 0], a0);
        a1 = fmaf(xv.y, wreg[4 * q4 + 1], a1);
        a2 = fmaf(xv.z, wreg[4 * q4 + 2], a2);
        a3 = fmaf(xv.w, wreg[4 * q4 + 3], a3);
      }
      float acc = (a0 + a1) + (a2 + a3);
      xp[n * 66 + lane] = f2bf(acc);
      float ps = acc * atts, pd = acc * attd;
      #pragma unroll
      for (int off = 32; off; off >>= 1) {
        ps += __shfl_xor(ps, off);
        pd += __shfl_xor(pd, off);
      }
      if (lane == 0) { as_[n] = ps; ad_[n] = pd; }
    }
  }
  __syncthreads();
  // ---- phase 2: per-edge leaky logits
  for (int d = tid; d < N_NODES; d += 256) {
    int rb = rowp[d], re = rowp[d + 1];
    float adv = ad_[d];
    for (int e = rb; e < re; ++e) {
      float v = as_[cols[e]] + adv;
      lw[e] = f2bf((v >= 0.f) ? v : 0.2f * v);
    }
  }
  __syncthreads();
  // ---- speed-head weights into regs: lane half qh covers q in [qh*32, qh*32+32)
  const int j = lane & 31, qh = lane >> 5;
  float sw1r[32];
  #pragma unroll
  for (int q = 0; q < 32; ++q) sw1r[q] = shw1[(qh * 32 + q) * 32 + j];
  const float sw2r = shw2[j];
  const float sb1r = shb1[j];
  const float sb2  = shb2[0];
  // ---- phase 3: aggregate + relu -> delta_recent; +H_base; speed head
  for (int d = wv; d < N_NODES; d += 4) {
    int rb = __builtin_amdgcn_readfirstlane(rowp[d]);
    int re = __builtin_amdgcn_readfirstlane(rowp[d + 1]);
    size_t base = (size_t)c * (N_NODES * 64) + (size_t)d * 64 + lane;
    float hbv = Hb[base];                      // prefetch before chain
    float dn0 = 0.f, dn1 = 0.f, dn2 = 0.f, dn3 = 0.f;
    float ac0 = 0.f, ac1 = 0.f, ac2 = 0.f, ac3 = 0.f;
    for (int e0 = rb; e0 < re; e0 += 4) {
      int e1 = e0 + 1, e2 = e0 + 2, e3 = e0 + 3;
      bool k1 = e1 < re, k2 = e2 < re, k3 = e3 < re;
      int s0 = cols[e0];
      int s1 = cols[k1 ? e1 : e0];
      int s2 = cols[k2 ? e2 : e0];
      int s3 = cols[k3 ? e3 : e0];
      float w0 = __expf(bf2f(lw[e0]));
      float w1 = k1 ? __expf(bf2f(lw[e1])) : 0.f;
      float w2 = k2 ? __expf(bf2f(lw[e2])) : 0.f;
      float w3 = k3 ? __expf(bf2f(lw[e3])) : 0.f;
      dn0 += w0; dn1 += w1; dn2 += w2; dn3 += w3;
      ac0 = fmaf(w0, bf2f(xp[s0 * 66 + lane]), ac0);
      ac1 = fmaf(w1, bf2f(xp[s1 * 66 + lane]), ac1);
      ac2 = fmaf(w2, bf2f(xp[s2 * 66 + lane]), ac2);
      ac3 = fmaf(w3, bf2f(xp[s3 * 66 + lane]), ac3);
    }
    float den = (dn0 + dn1) + (dn2 + dn3);
    float acc = (ac0 + ac1) + (ac2 + ac3);
    float val = fmaxf(acc / (den + 1e-16f) + blane, 0.f);
    dR[base] = val;
    float had = hbv + val;
    Ha[base] = had;
    hv[wv][lane] = had;
    // speed head: q split across lane halves, 4 independent FMA chains
    float p0 = 0.f, p1 = 0.f, p2 = 0.f, p3 = 0.f;
    const float* hrow = &hv[wv][qh * 32];
    #pragma unroll
    for (int q = 0; q < 32; q += 4) {
      p0 = fmaf(hrow[q + 0], sw1r[q + 0], p0);
      p1 = fmaf(hrow[q + 1], sw1r[q + 1], p1);
      p2 = fmaf(hrow[q + 2], sw1r[q + 2], p2);
      p3 = fmaf(hrow[q + 3], sw1r[q + 3], p3);
    }
    float a = (p0 + p1) + (p2 + p3);
    a += __shfl_xor(a, 32);                    // combine q-halves: lanes j, j+32 hold full a_j
    a = fmaxf(a + sb1r, 0.f) * sw2r;
    #pragma unroll
    for (int off = 16; off; off >>= 1) a += __shfl_xor(a, off);  // sum over j within half
    if (lane == 0) pred[c * N_NODES + d] = a + sb2;
  }
}

extern "C" void kernel_launch(void* const* d_in, const int* in_sizes, int n_in,
                              void* d_out, int out_size, void* d_ws, size_t ws_size,
                              hipStream_t stream) {
  const float* Hb    = (const float*)d_in[0];
  const float* seq   = (const float*)d_in[1];
  const int*   ei    = (const int*)d_in[2];
  const float* gwih  = (const float*)d_in[3];
  const float* gwhh  = (const float*)d_in[4];
  const float* gbih  = (const float*)d_in[5];
  const float* gbhh  = (const float*)d_in[6];
  const float* rw1   = (const float*)d_in[7];
  const float* rb1   = (const float*)d_in[8];
  const float* rw2   = (const float*)d_in[9];
  const float* rb2   = (const float*)d_in[10];
  const float* wemb  = (const float*)d_in[11];
  const float* semb  = (const float*)d_in[12];
  const float* cw1   = (const float*)d_in[13];
  const float* cb1   = (const float*)d_in[14];
  const float* cw2   = (const float*)d_in[15];
  const float* cb2   = (const float*)d_in[16];
  const float* dw1   = (const float*)d_in[17];
  const float* db1   = (const float*)d_in[18];
  const float* dw2   = (const float*)d_in[19];
  const float* db2   = (const float*)d_in[20];
  const float* gmw   = (const float*)d_in[21];
  const float* gmb   = (const float*)d_in[22];
  const float* g1w   = (const float*)d_in[23];
  const float* g1as  = (const float*)d_in[24];
  const float* g1ad  = (const float*)d_in[25];
  const float* g1b   = (const float*)d_in[26];
  const float* g2w   = (const float*)d_in[27];
  const float* g2as  = (const float*)d_in[28];
  const float* g2ad  = (const float*)d_in[29];
  const float* g2b   = (const float*)d_in[30];
  const float* shw1  = (const float*)d_in[31];
  const float* shb1  = (const float*)d_in[32];
  const float* shw2  = (const float*)d_in[33];
  const float* shb2  = (const float*)d_in[34];

  float* out = (float*)d_out;
  float* region0 = out;                     // final: delta_recent_bank
  float* region1 = out + 41932800u;         // final: H_adapted_bank
  float* region2 = out + 83865600u;         // final: pred_speed_bank

  // scratch choreography: delta -> region1, GAT1 out -> region0,
  // GAT2 overwrites region0 (delta_recent) + region1 (H_adapted) + region2.
  float* delta = region1;
  float* y1    = region0;

  int* rowp = (int*)d_ws;                   // [326]
  int* cols = rowp + 384;                   // [2925]
  float* recent = (float*)(rowp + 3328);    // [325*32]
  float* cal    = recent + 10400;           // [2016*32]

  k_csr<<<1, 512, 0, stream>>>(ei, rowp, cols);
  k_gru<<<(N_NODES + 7) / 8, 256, 0, stream>>>(seq, gwih, gwhh, gbih, gbhh,
                                               rw1, rb1, rw2, rb2, recent);
  k_cal<<<GTOT / 8, 256, 0, stream>>>(wemb, semb, cw1, cb1, cw2, cb2, cal);
  k_fusion<<<(NPOS + 63) / 64, 256, 0, stream>>>(Hb, recent, cal,
                                                 dw1, db1, dw2, db2, gmw, gmb, delta);
  k_gat1<<<GTOT, 256, 0, stream>>>(delta, rowp, cols, g1w, g1as, g1ad, g1b, y1);
  k_gat2<<<GTOT, 256, 0, stream>>>(y1, Hb, rowp, cols, g2w, g2as, g2ad, g2b,
                                   shw1, shb1, shw2, shb2,
                                   region0, region1, region2);
}